// Round 5
// baseline (37.179 us; speedup 1.0000x reference)
//
#include <hip/hip_runtime.h>
#include <hip/hip_bf16.h>

#define N 4096
#define D 256
#define MARGIN 0.3f
#define NSLOT 33
#define FLT_BIG 3.402823466e+38f

typedef __attribute__((ext_vector_type(8))) short short8;
typedef __attribute__((ext_vector_type(4))) float f32x4;
typedef const __attribute__((address_space(1))) unsigned char g1_t;
typedef __attribute__((address_space(3))) unsigned char l3_t;

__device__ __forceinline__ ushort f2bf(float f) {
    unsigned u = __float_as_uint(f);
    unsigned r = (u + 0x7fffu + ((u >> 16) & 1u)) >> 16;   // RNE
    return (ushort)r;
}

// Kernel 1: per-row squared norms (fp32, exact), bf16 cast, init accumulators.
__global__ __launch_bounds__(256) void prep_kernel(
        const float* __restrict__ feat,
        float* __restrict__ xx,
        ushort* __restrict__ hi,
        float* __restrict__ gacc,      // [0]=sum, [1]=cnt
        unsigned* __restrict__ ticket) {
    if (blockIdx.x == 0 && threadIdx.x == 0) {
        gacc[0] = 0.0f; gacc[1] = 0.0f; *ticket = 0u;
    }
    int row  = blockIdx.x * 4 + (threadIdx.x >> 6);
    int lane = threadIdx.x & 63;
    float4 v = *(const float4*)(feat + row * D + lane * 4);
    *(ushort4*)(hi + row * D + lane * 4) =
        make_ushort4(f2bf(v.x), f2bf(v.y), f2bf(v.z), f2bf(v.w));
    float s = v.x * v.x + v.y * v.y + v.z * v.z + v.w * v.w;
    #pragma unroll
    for (int off = 32; off >= 1; off >>= 1) s += __shfl_xor(s, off);
    if (lane == 0) xx[row] = s;
}

// Kernel 2: triangular 128x128 bf16-MFMA tiles, double-buffered staging.
// Block (bi,bj), bj>=bi: row-wise masked max/min -> partial slot bj+1 (1..32),
// col-wise -> slot bi (0..bj). For each panel p, slots 0..32 are each written
// exactly once (col-wise: 0..p, row-wise: p+1..32) -> no init, no atomics.
__global__ __launch_bounds__(256, 2) void dist_mfma_kernel(
        const ushort* __restrict__ hi,
        const int* __restrict__ labels, const float* __restrict__ xx,
        float* __restrict__ pPart, float* __restrict__ nPart) {
    __shared__ __attribute__((aligned(16))) short sA[2][128 * 64];
    __shared__ __attribute__((aligned(16))) short sB[2][128 * 64];
    __shared__ float rp[4][64], rn[4][64], cp[4][64], cn[4][64];

    // triangular decode: blockIdx.x -> (bi, bj) with bj >= bi
    int t = blockIdx.x, bi = 0, rem = 32;
    while (t >= rem) { t -= rem; ++bi; --rem; }
    const int bj = bi + t;
    const int rowBase = bi * 128;
    const int colBase = bj * 128;

    const int tid  = threadIdx.x;
    const int lane = tid & 63;
    const int wid  = tid >> 6;
    const int wr   = (wid >> 1) * 64;      // wave row offset
    const int wc   = (wid & 1) * 64;       // wave col offset
    const int l15  = lane & 15;
    const int kq   = (lane >> 4) * 8;
    const int swz  = (lane & 7) << 3;

    f32x4 acc[4][4] = {};

    auto stage = [&](int b, int kt) {
        #pragma unroll
        for (int i = 0; i < 4; ++i) {
            int c   = i * 256 + tid;          // 16B chunk index
            int row = c >> 3;
            int kc  = ((c ^ row) & 7) * 8;    // pre-swizzled global k-chunk
            __builtin_amdgcn_global_load_lds(
                (g1_t*)(hi + (size_t)(rowBase + row) * D + kt + kc),
                (l3_t*)(&sA[b][c * 8]), 16, 0, 0);
            __builtin_amdgcn_global_load_lds(
                (g1_t*)(hi + (size_t)(colBase + row) * D + kt + kc),
                (l3_t*)(&sB[b][c * 8]), 16, 0, 0);
        }
    };

    stage(0, 0);
    __syncthreads();
    int cur = 0;
    for (int step = 0; step < 4; ++step) {
        if (step < 3) stage(cur ^ 1, (step + 1) * 64);
        #pragma unroll
        for (int h = 0; h < 2; ++h) {
            short8 af[4], bfv[4];
            #pragma unroll
            for (int m = 0; m < 4; ++m) {
                int idx = ((wr + m * 16 + l15) << 6) + h * 32 + kq;
                af[m] = *(const short8*)(&sA[cur][idx ^ swz]);
            }
            #pragma unroll
            for (int n = 0; n < 4; ++n) {
                int idx = ((wc + n * 16 + l15) << 6) + h * 32 + kq;
                bfv[n] = *(const short8*)(&sB[cur][idx ^ swz]);
            }
            #pragma unroll
            for (int m = 0; m < 4; ++m)
                #pragma unroll
                for (int n = 0; n < 4; ++n)
                    acc[m][n] = __builtin_amdgcn_mfma_f32_16x16x32_bf16(
                        af[m], bfv[n], acc[m][n], 0, 0, 0);
        }
        __syncthreads();      // drains vmcnt: next buffer ready; reads done
        cur ^= 1;
    }

    // Epilogue in d^2 domain (sqrt deferred; monotone).
    float xr[4][4]; int lrow[4][4];
    #pragma unroll
    for (int m = 0; m < 4; ++m)
        #pragma unroll
        for (int j = 0; j < 4; ++j) {
            int rg = rowBase + wr + m * 16 + (lane >> 4) * 4 + j;
            xr[m][j] = xx[rg]; lrow[m][j] = labels[rg];
        }
    float xc[4]; int lcol[4];
    #pragma unroll
    for (int n = 0; n < 4; ++n) {
        int cg = colBase + wc + n * 16 + l15;
        xc[n] = xx[cg]; lcol[n] = labels[cg];
    }

    float pm2[4][4], nm2[4][4];   // row-wise
    float cpm[4],   cnm[4];       // col-wise
    #pragma unroll
    for (int m = 0; m < 4; ++m)
        #pragma unroll
        for (int j = 0; j < 4; ++j) { pm2[m][j] = 0.0f; nm2[m][j] = FLT_BIG; }
    #pragma unroll
    for (int n = 0; n < 4; ++n) { cpm[n] = 0.0f; cnm[n] = FLT_BIG; }

    #pragma unroll
    for (int m = 0; m < 4; ++m)
        #pragma unroll
        for (int n = 0; n < 4; ++n)
            #pragma unroll
            for (int j = 0; j < 4; ++j) {
                float d2 = fmaxf(xr[m][j] + xc[n] - 2.0f * acc[m][n][j], 0.0f);
                bool pos = (lrow[m][j] == lcol[n]);
                if (pos) {
                    pm2[m][j] = fmaxf(pm2[m][j], d2);
                    cpm[n]    = fmaxf(cpm[n],    d2);
                } else {
                    nm2[m][j] = fminf(nm2[m][j], d2);
                    cnm[n]    = fminf(cnm[n],    d2);
                }
            }

    // row-wise: reduce over the 16 column-lanes (bits 0..3)
    #pragma unroll
    for (int m = 0; m < 4; ++m)
        #pragma unroll
        for (int j = 0; j < 4; ++j) {
            #pragma unroll
            for (int off = 1; off <= 8; off <<= 1) {
                pm2[m][j] = fmaxf(pm2[m][j], __shfl_xor(pm2[m][j], off));
                nm2[m][j] = fminf(nm2[m][j], __shfl_xor(nm2[m][j], off));
            }
        }
    // col-wise: reduce over the 4 row-lane-groups (bits 4..5)
    #pragma unroll
    for (int n = 0; n < 4; ++n) {
        #pragma unroll
        for (int off = 16; off <= 32; off <<= 1) {
            cpm[n] = fmaxf(cpm[n], __shfl_xor(cpm[n], off));
            cnm[n] = fminf(cnm[n], __shfl_xor(cnm[n], off));
        }
    }

    // stash per-wave results in LDS for cross-wave merge
    if (l15 == 0) {
        #pragma unroll
        for (int m = 0; m < 4; ++m)
            #pragma unroll
            for (int j = 0; j < 4; ++j) {
                int r = m * 16 + (lane >> 4) * 4 + j;   // 0..63
                rp[wid][r] = pm2[m][j]; rn[wid][r] = nm2[m][j];
            }
    }
    if (lane < 16) {
        #pragma unroll
        for (int n = 0; n < 4; ++n) {
            int c = n * 16 + l15;                        // 0..63
            cp[wid][c] = cpm[n]; cn[wid][c] = cnm[n];
        }
    }
    __syncthreads();

    // coalesced partial stores: waves (0,1)/(2,3) share rows; (0,2)/(1,3) share cols
    if (tid < 128) {
        int half = tid >> 6, r = tid & 63;
        float p = fmaxf(rp[2 * half][r], rp[2 * half + 1][r]);
        float q = fminf(rn[2 * half][r], rn[2 * half + 1][r]);
        pPart[(size_t)(bj + 1) * N + rowBase + tid] = p;
        nPart[(size_t)(bj + 1) * N + rowBase + tid] = q;
    } else {
        int tc = tid - 128, half = tc >> 6, c = tc & 63;
        float p = fmaxf(cp[half][c], cp[half + 2][c]);
        float q = fminf(cn[half][c], cn[half + 2][c]);
        pPart[(size_t)bi * N + colBase + tc] = p;
        nPart[(size_t)bi * N + colBase + tc] = q;
    }
}

// Kernel 3: merge 33 partial slots per row, margin-ranking loss, ticketed finalize.
__global__ __launch_bounds__(256) void merge_kernel(
        const float* __restrict__ pPart, const float* __restrict__ nPart,
        float* __restrict__ gacc, unsigned* __restrict__ ticket,
        float* __restrict__ out) {
    __shared__ float ssum[4], scnt[4];
    int i = blockIdx.x * 256 + threadIdx.x;
    float ap2 = 0.0f, an2 = FLT_BIG;
    #pragma unroll 3
    for (int s = 0; s < NSLOT; ++s) {
        ap2 = fmaxf(ap2, pPart[(size_t)s * N + i]);
        an2 = fminf(an2, nPart[(size_t)s * N + i]);
    }
    float ap = sqrtf(fmaxf(ap2, 1e-12f));
    float an = sqrtf(fmaxf(an2, 1e-12f));
    bool valid = (ap < 1.0e6f) && (an > 0.0f);
    float per = valid ? fmaxf(MARGIN + ap - an, 0.0f) : 0.0f;
    float cnt = valid ? 1.0f : 0.0f;
    #pragma unroll
    for (int off = 32; off >= 1; off >>= 1) {
        per += __shfl_xor(per, off);
        cnt += __shfl_xor(cnt, off);
    }
    int tid = threadIdx.x, wv = tid >> 6;
    if ((tid & 63) == 0) { ssum[wv] = per; scnt[wv] = cnt; }
    __syncthreads();
    if (tid == 0) {
        float S = ssum[0] + ssum[1] + ssum[2] + ssum[3];
        float C = scnt[0] + scnt[1] + scnt[2] + scnt[3];
        atomicAdd(&gacc[0], S);
        atomicAdd(&gacc[1], C);
        __threadfence();
        unsigned tk = atomicAdd(ticket, 1u);
        if (tk == gridDim.x - 1) {       // last block: all adds visible
            float St = atomicAdd(&gacc[0], 0.0f);
            float Ct = atomicAdd(&gacc[1], 0.0f);
            out[0] = (Ct > 0.0f) ? St / fmaxf(Ct, 1.0f) : 0.0f;
        }
    }
}

extern "C" void kernel_launch(void* const* d_in, const int* in_sizes, int n_in,
                              void* d_out, int out_size, void* d_ws, size_t ws_size,
                              hipStream_t stream) {
    const float* feat = (const float*)d_in[0];
    const int* labels = (const int*)d_in[1];
    char* ws = (char*)d_ws;
    float*    xx     = (float*)ws;                                   // 16 KB
    float*    gacc   = (float*)(ws + 16384);                         // 8 B
    unsigned* ticket = (unsigned*)(ws + 16384 + 8);                  // 4 B
    ushort*   hi     = (ushort*)(ws + 32768);                        // 2 MB
    float*    pPart  = (float*)(ws + 32768 + (size_t)N * D * 2);     // 528 KB
    float*    nPart  = (float*)(ws + 32768 + (size_t)N * D * 2
                                + (size_t)NSLOT * N * 4);            // 528 KB
    float* out = (float*)d_out;

    prep_kernel<<<N / 4, 256, 0, stream>>>(feat, xx, hi, gacc, ticket);
    dist_mfma_kernel<<<528, 256, 0, stream>>>(hi, labels, xx, pPart, nPart);
    merge_kernel<<<N / 256, 256, 0, stream>>>(pPart, nPart, gacc, ticket, out);
}

// Round 6
// 36.002 us; speedup vs baseline: 1.0327x; 1.0327x over previous
//
#include <hip/hip_runtime.h>
#include <hip/hip_bf16.h>

#define N 4096
#define D 256
#define MARGIN 0.3f
#define NPANEL 64          // 4096 / 64
#define NSLOT 65           // partial slots per panel: 0..64, each written once
#define FLT_BIG 3.402823466e+38f

typedef __attribute__((ext_vector_type(8))) short short8;
typedef __attribute__((ext_vector_type(4))) float f32x4;
typedef const __attribute__((address_space(1))) unsigned char g1_t;
typedef __attribute__((address_space(3))) unsigned char l3_t;

__device__ __forceinline__ ushort f2bf(float f) {
    unsigned u = __float_as_uint(f);
    unsigned r = (u + 0x7fffu + ((u >> 16) & 1u)) >> 16;   // RNE
    return (ushort)r;
}

// Kernel 1: per-row squared norms (fp32, exact), bf16 cast, init accumulators.
__global__ __launch_bounds__(256) void prep_kernel(
        const float* __restrict__ feat,
        float* __restrict__ xx,
        ushort* __restrict__ hi,
        float* __restrict__ gacc,      // [0]=sum, [1]=cnt
        unsigned* __restrict__ ticket) {
    if (blockIdx.x == 0 && threadIdx.x == 0) {
        gacc[0] = 0.0f; gacc[1] = 0.0f; *ticket = 0u;
    }
    int row  = blockIdx.x * 4 + (threadIdx.x >> 6);
    int lane = threadIdx.x & 63;
    float4 v = *(const float4*)(feat + row * D + lane * 4);
    *(ushort4*)(hi + row * D + lane * 4) =
        make_ushort4(f2bf(v.x), f2bf(v.y), f2bf(v.z), f2bf(v.w));
    float s = v.x * v.x + v.y * v.y + v.z * v.z + v.w * v.w;
    #pragma unroll
    for (int off = 32; off >= 1; off >>= 1) s += __shfl_xor(s, off);
    if (lane == 0) xx[row] = s;
}

// Kernel 2: triangular 64x64 bf16-MFMA tiles, single-buffered, small footprint
// for max occupancy (latency-bound regime: TLP hides stage latency).
// Block (bi,bj), bj>=bi: row-wise masked max/min -> slot bj+1 (1..64),
// col-wise -> slot bi (0..63). Per panel p: col-wise 0..p, row-wise p+1..64
// -> slots 0..64 each written exactly once. No init, no atomics.
__global__ __launch_bounds__(256, 6) void dist_mfma_kernel(
        const ushort* __restrict__ hi,
        const int* __restrict__ labels, const float* __restrict__ xx,
        float* __restrict__ pPart, float* __restrict__ nPart) {
    __shared__ __attribute__((aligned(16))) short sA[64 * 64];   // 8 KB
    __shared__ __attribute__((aligned(16))) short sB[64 * 64];   // 8 KB
    __shared__ float rp[4][32], rn[4][32], cp[4][32], cn[4][32]; // 2 KB

    // triangular decode: blockIdx.x -> (bi, bj) with bj >= bi, 64 panels
    int t = blockIdx.x, bi = 0, rem = NPANEL;
    while (t >= rem) { t -= rem; ++bi; --rem; }
    const int bj = bi + t;
    const int rowBase = bi * 64;
    const int colBase = bj * 64;

    const int tid  = threadIdx.x;
    const int lane = tid & 63;
    const int wid  = tid >> 6;
    const int wr   = (wid >> 1) * 32;      // wave row quadrant
    const int wc   = (wid & 1) * 32;       // wave col quadrant
    const int l15  = lane & 15;
    const int kq   = (lane >> 4) * 8;
    const int swz  = (lane & 7) << 3;      // ushort-index XOR swizzle (16B units)

    f32x4 acc[2][2] = {};

    for (int kt = 0; kt < D; kt += 64) {
        // stage 64x64 bf16 A and B tiles (2 chunks/thread/matrix)
        #pragma unroll
        for (int i = 0; i < 2; ++i) {
            int c   = i * 256 + tid;          // 16B chunk index, 0..511
            int row = c >> 3;                 // 0..63
            int kc  = ((c ^ row) & 7) * 8;    // pre-swizzled global k-chunk
            __builtin_amdgcn_global_load_lds(
                (g1_t*)(hi + (size_t)(rowBase + row) * D + kt + kc),
                (l3_t*)(sA + c * 8), 16, 0, 0);
            __builtin_amdgcn_global_load_lds(
                (g1_t*)(hi + (size_t)(colBase + row) * D + kt + kc),
                (l3_t*)(sB + c * 8), 16, 0, 0);
        }
        __syncthreads();
        #pragma unroll
        for (int h = 0; h < 2; ++h) {
            short8 af[2], bfv[2];
            #pragma unroll
            for (int m = 0; m < 2; ++m) {
                int idx = ((wr + m * 16 + l15) << 6) + h * 32 + kq;
                af[m] = *(const short8*)(sA + (idx ^ swz));
            }
            #pragma unroll
            for (int n = 0; n < 2; ++n) {
                int idx = ((wc + n * 16 + l15) << 6) + h * 32 + kq;
                bfv[n] = *(const short8*)(sB + (idx ^ swz));
            }
            #pragma unroll
            for (int m = 0; m < 2; ++m)
                #pragma unroll
                for (int n = 0; n < 2; ++n)
                    acc[m][n] = __builtin_amdgcn_mfma_f32_16x16x32_bf16(
                        af[m], bfv[n], acc[m][n], 0, 0, 0);
        }
        __syncthreads();
    }

    // Epilogue in d^2 domain (sqrt deferred; monotone).
    float xr[2][4]; int lrow[2][4];
    #pragma unroll
    for (int m = 0; m < 2; ++m)
        #pragma unroll
        for (int j = 0; j < 4; ++j) {
            int rg = rowBase + wr + m * 16 + (lane >> 4) * 4 + j;
            xr[m][j] = xx[rg]; lrow[m][j] = labels[rg];
        }
    float xc[2]; int lcol[2];
    #pragma unroll
    for (int n = 0; n < 2; ++n) {
        int cg = colBase + wc + n * 16 + l15;
        xc[n] = xx[cg]; lcol[n] = labels[cg];
    }

    float pm2[2][4], nm2[2][4];   // row-wise
    float cpm[2],    cnm[2];      // col-wise
    #pragma unroll
    for (int m = 0; m < 2; ++m)
        #pragma unroll
        for (int j = 0; j < 4; ++j) { pm2[m][j] = 0.0f; nm2[m][j] = FLT_BIG; }
    #pragma unroll
    for (int n = 0; n < 2; ++n) { cpm[n] = 0.0f; cnm[n] = FLT_BIG; }

    #pragma unroll
    for (int m = 0; m < 2; ++m)
        #pragma unroll
        for (int n = 0; n < 2; ++n)
            #pragma unroll
            for (int j = 0; j < 4; ++j) {
                float d2 = fmaxf(xr[m][j] + xc[n] - 2.0f * acc[m][n][j], 0.0f);
                bool pos = (lrow[m][j] == lcol[n]);
                if (pos) {
                    pm2[m][j] = fmaxf(pm2[m][j], d2);
                    cpm[n]    = fmaxf(cpm[n],    d2);
                } else {
                    nm2[m][j] = fminf(nm2[m][j], d2);
                    cnm[n]    = fminf(cnm[n],    d2);
                }
            }

    // row-wise: reduce over the 16 column-lanes (bits 0..3)
    #pragma unroll
    for (int m = 0; m < 2; ++m)
        #pragma unroll
        for (int j = 0; j < 4; ++j) {
            #pragma unroll
            for (int off = 1; off <= 8; off <<= 1) {
                pm2[m][j] = fmaxf(pm2[m][j], __shfl_xor(pm2[m][j], off));
                nm2[m][j] = fminf(nm2[m][j], __shfl_xor(nm2[m][j], off));
            }
        }
    // col-wise: reduce over the 4 row-lane-groups (bits 4..5)
    #pragma unroll
    for (int n = 0; n < 2; ++n) {
        #pragma unroll
        for (int off = 16; off <= 32; off <<= 1) {
            cpm[n] = fmaxf(cpm[n], __shfl_xor(cpm[n], off));
            cnm[n] = fminf(cnm[n], __shfl_xor(cnm[n], off));
        }
    }

    // stash per-wave results in LDS for cross-wave merge
    if (l15 == 0) {
        #pragma unroll
        for (int m = 0; m < 2; ++m)
            #pragma unroll
            for (int j = 0; j < 4; ++j) {
                int r = m * 16 + (lane >> 4) * 4 + j;   // 0..31
                rp[wid][r] = pm2[m][j]; rn[wid][r] = nm2[m][j];
            }
    }
    if (lane < 16) {
        #pragma unroll
        for (int n = 0; n < 2; ++n) {
            int c = n * 16 + l15;                        // 0..31
            cp[wid][c] = cpm[n]; cn[wid][c] = cnm[n];
        }
    }
    __syncthreads();

    // merged partial stores:
    // rows: waves (0,1) cover rows 0..31, waves (2,3) rows 32..63
    // cols: waves (0,2) cover cols 0..31, waves (1,3) cols 32..63
    if (tid < 64) {
        int r = tid, pair = (r >> 5) * 2, rr = r & 31;
        float p = fmaxf(rp[pair][rr], rp[pair + 1][rr]);
        float q = fminf(rn[pair][rr], rn[pair + 1][rr]);
        pPart[(size_t)(bj + 1) * N + rowBase + r] = p;
        nPart[(size_t)(bj + 1) * N + rowBase + r] = q;
    } else if (tid < 128) {
        int c = tid - 64, pair = c >> 5, cc = c & 31;
        float p = fmaxf(cp[pair][cc], cp[pair + 2][cc]);
        float q = fminf(cn[pair][cc], cn[pair + 2][cc]);
        pPart[(size_t)bi * N + colBase + c] = p;
        nPart[(size_t)bi * N + colBase + c] = q;
    }
}

// Kernel 3: merge 65 partial slots per row, margin-ranking loss, ticketed finalize.
__global__ __launch_bounds__(256) void merge_kernel(
        const float* __restrict__ pPart, const float* __restrict__ nPart,
        float* __restrict__ gacc, unsigned* __restrict__ ticket,
        float* __restrict__ out) {
    __shared__ float ssum[4], scnt[4];
    int i = blockIdx.x * 256 + threadIdx.x;
    float ap2 = 0.0f, an2 = FLT_BIG;
    #pragma unroll 5
    for (int s = 0; s < NSLOT; ++s) {
        ap2 = fmaxf(ap2, pPart[(size_t)s * N + i]);
        an2 = fminf(an2, nPart[(size_t)s * N + i]);
    }
    float ap = sqrtf(fmaxf(ap2, 1e-12f));
    float an = sqrtf(fmaxf(an2, 1e-12f));
    bool valid = (ap < 1.0e6f) && (an > 0.0f);
    float per = valid ? fmaxf(MARGIN + ap - an, 0.0f) : 0.0f;
    float cnt = valid ? 1.0f : 0.0f;
    #pragma unroll
    for (int off = 32; off >= 1; off >>= 1) {
        per += __shfl_xor(per, off);
        cnt += __shfl_xor(cnt, off);
    }
    int tid = threadIdx.x, wv = tid >> 6;
    if ((tid & 63) == 0) { ssum[wv] = per; scnt[wv] = cnt; }
    __syncthreads();
    if (tid == 0) {
        float S = ssum[0] + ssum[1] + ssum[2] + ssum[3];
        float C = scnt[0] + scnt[1] + scnt[2] + scnt[3];
        atomicAdd(&gacc[0], S);
        atomicAdd(&gacc[1], C);
        __threadfence();
        unsigned tk = atomicAdd(ticket, 1u);
        if (tk == gridDim.x - 1) {       // last block: all adds visible
            float St = atomicAdd(&gacc[0], 0.0f);
            float Ct = atomicAdd(&gacc[1], 0.0f);
            out[0] = (Ct > 0.0f) ? St / fmaxf(Ct, 1.0f) : 0.0f;
        }
    }
}

extern "C" void kernel_launch(void* const* d_in, const int* in_sizes, int n_in,
                              void* d_out, int out_size, void* d_ws, size_t ws_size,
                              hipStream_t stream) {
    const float* feat = (const float*)d_in[0];
    const int* labels = (const int*)d_in[1];
    char* ws = (char*)d_ws;
    float*    xx     = (float*)ws;                                   // 16 KB
    float*    gacc   = (float*)(ws + 16384);                         // 8 B
    unsigned* ticket = (unsigned*)(ws + 16384 + 8);                  // 4 B
    ushort*   hi     = (ushort*)(ws + 32768);                        // 2 MB
    float*    pPart  = (float*)(ws + 32768 + (size_t)N * D * 2);     // 1.07 MB
    float*    nPart  = (float*)(ws + 32768 + (size_t)N * D * 2
                                + (size_t)NSLOT * N * 4);            // 1.07 MB
    float* out = (float*)d_out;

    prep_kernel<<<N / 4, 256, 0, stream>>>(feat, xx, hi, gacc, ticket);
    dist_mfma_kernel<<<NPANEL * (NPANEL + 1) / 2, 256, 0, stream>>>(
        hi, labels, xx, pPart, nPart);
    merge_kernel<<<N / 256, 256, 0, stream>>>(pPart, nPart, gacc, ticket, out);
}